// Round 4
// baseline (121.089 us; speedup 1.0000x reference)
//
#include <hip/hip_runtime.h>
#include <math.h>

// Problem constants (fixed by the reference file)
constexpr int B  = 1024;
constexpr int NL = 64;
constexpr int W  = 2048;
constexpr int INNER = NL - 2;   // layers 1..62
constexpr int NG = INNER / 2;   // 31 layer-pairs
constexpr float EPS_N = 1e-8f;
constexpr float EPS_Y = 1e-9f;

typedef float v2f __attribute__((ext_vector_type(2)));

// ---- VOP3P packed-f32 inline asm (guaranteed v_pk_* emission) ----
#define PK_MUL(d,a,b)   asm("v_pk_mul_f32 %0, %1, %2" : "=v"(d) : "v"(a), "v"(b))
#define PK_ADD(d,a,b)   asm("v_pk_add_f32 %0, %1, %2" : "=v"(d) : "v"(a), "v"(b))
#define PK_SUB(d,a,b)   asm("v_pk_add_f32 %0, %1, %2 neg_lo:[0,1] neg_hi:[0,1]" : "=v"(d) : "v"(a), "v"(b))
#define PK_FMA(d,a,b,c) asm("v_pk_fma_f32 %0, %1, %2, %3" : "=v"(d) : "v"(a), "v"(b), "v"(c))
// src1 broadcast from its LO (or HI) register to both result halves, with a
// sign flip on one half (the (x,-x) pattern of the transfer-matrix update).
#define PK_MUL_BCLO(d,a,b) \
  asm("v_pk_mul_f32 %0, %1, %2 op_sel:[0,0] op_sel_hi:[1,0]" : "=v"(d) : "v"(a), "v"(b))
#define PK_MUL_BCHI(d,a,b) \
  asm("v_pk_mul_f32 %0, %1, %2 op_sel:[0,1] op_sel_hi:[1,1]" : "=v"(d) : "v"(a), "v"(b))
#define PK_FMA_BCLO_NEGHI(d,a,b,c) \
  asm("v_pk_fma_f32 %0, %1, %2, %3 op_sel:[0,0,0] op_sel_hi:[1,0,1] neg_hi:[0,1,0]" : "=v"(d) : "v"(a), "v"(b), "v"(c))
#define PK_FMA_BCHI_NEGHI(d,a,b,c) \
  asm("v_pk_fma_f32 %0, %1, %2, %3 op_sel:[0,1,0] op_sel_hi:[1,1,1] neg_hi:[0,1,0]" : "=v"(d) : "v"(a), "v"(b), "v"(c))
#define PK_FMA_BCLO_NEGLO(d,a,b,c) \
  asm("v_pk_fma_f32 %0, %1, %2, %3 op_sel:[0,0,0] op_sel_hi:[1,0,1] neg_lo:[0,1,0]" : "=v"(d) : "v"(a), "v"(b), "v"(c))
#define PK_FMA_BCHI_NEGLO(d,a,b,c) \
  asm("v_pk_fma_f32 %0, %1, %2, %3 op_sel:[0,1,0] op_sel_hi:[1,1,1] neg_lo:[0,1,0]" : "=v"(d) : "v"(a), "v"(b), "v"(c))

// sin(pi*x) Taylor (odd, deg 11), x in [-0.5, 0.5]
#define A0 3.14159265358979f
#define A1 -5.16771278004997f
#define A2 2.55016403987735f
#define A3 -0.599264529320792f
#define A4 0.0821458866111282f
#define A5 -0.00737043094571435f
// cos(pi*x) Taylor (even, deg 10), x in [-0.5, 0.5]
#define B0 1.0f
#define B1 -4.93480220054468f
#define B2 4.05871212641677f
#define B3 -1.33526276885459f
#define B4 0.235330630358514f
#define B5 -0.0258068914490399f

// One thread per (b, w). Layers processed in independent PAIRS: both sincos
// of a pair computed with packed (2-wide) polynomial on the full-rate VALU
// (v_pk_*), replacing the quarter-rate v_sin/v_cos trans ops that consumed
// ~57% of issue. phi tracked in revolutions; reduction r = phi - rint(phi);
// half-angle: sh=sin(pi r), ch=cos(pi r) -> s=2 sh ch, c=1-2 sh^2.
// Matrix state p=(a,c), q=(b,d): per layer (lane L of the pair):
//   p' = q*(ns_L, -ns_L) + p*c_L ;  q' = p_old*(-is_L, is_L) + q*c_L
// implemented as 4 v_pk ops with op_sel lane-broadcast + neg modifiers.
__global__ __launch_bounds__(256)
void tmm_kernel(const float* __restrict__ n_layers,
                const float* __restrict__ d_layers,
                const float* __restrict__ wavelengths,
                float* __restrict__ out)
{
    __shared__ v2f s_nd[NG];
    __shared__ v2f s_n[NG];
    __shared__ v2f s_rn[NG];
    __shared__ float s_edge[2];   // n_in, n_sub

    const int b   = blockIdx.y;
    const int tid = threadIdx.x;
    const int w   = blockIdx.x * 256 + tid;

    if (tid < NG) {
        const int base = b * NL + 1 + 2 * tid;   // layers 1+2t, 2+2t
        const float n0 = n_layers[base],     n1 = n_layers[base + 1];
        const float d0 = d_layers[base],     d1 = d_layers[base + 1];
        v2f nd = {n0 * d0, n1 * d1};
        v2f nn = {n0, n1};
        v2f rn = {1.0f / (n0 + EPS_N), 1.0f / (n1 + EPS_N)};
        s_nd[tid] = nd;
        s_n[tid]  = nn;
        s_rn[tid] = rn;
    }
    if (tid == NG) {
        s_edge[0] = n_layers[b * NL];             // n_in
        s_edge[1] = n_layers[b * NL + NL - 1];    // n_sub
    }
    __syncthreads();

    const float il = 1.0f / wavelengths[w];       // k0 in revolutions
    const v2f il2 = {il, il};
    const v2f A5P = {A5, A5}, A4P = {A4, A4}, A3P = {A3, A3},
              A2P = {A2, A2}, A1P = {A1, A1}, A0P = {A0, A0};
    const v2f B5P = {B5, B5}, B4P = {B4, B4}, B3P = {B3, B3},
              B2P = {B2, B2}, B1P = {B1, B1}, B0P = {B0, B0};
    const v2f ONEP = {1.0f, 1.0f};

    // p = (a, c), q = (b, d); M = [[a, i*b],[i*c, d]] starts as identity.
    v2f p = {1.0f, 0.0f};
    v2f q = {0.0f, 1.0f};

    #pragma unroll
    for (int g = 0; g < NG; ++g) {
        const v2f nd2 = s_nd[g];
        const v2f n2  = s_n[g];
        const v2f rn2 = s_rn[g];

        // packed phase + period reduction
        v2f phi; PK_MUL(phi, nd2, il2);
        v2f rnd = {__builtin_rintf(phi.x), __builtin_rintf(phi.y)};
        v2f r;   PK_SUB(r, phi, rnd);          // r in [-0.5, 0.5]
        v2f y2;  PK_MUL(y2, r, r);

        // sh = sin(pi r): r*(A0 + y2*(A1 + y2*(A2 + y2*(A3 + y2*(A4 + y2*A5)))))
        v2f sh;  PK_FMA(sh, y2, A5P, A4P);
                 PK_FMA(sh, y2, sh, A3P);
                 PK_FMA(sh, y2, sh, A2P);
                 PK_FMA(sh, y2, sh, A1P);
                 PK_FMA(sh, y2, sh, A0P);
                 PK_MUL(sh, sh, r);
        // ch = cos(pi r)
        v2f ch;  PK_FMA(ch, y2, B5P, B4P);
                 PK_FMA(ch, y2, ch, B3P);
                 PK_FMA(ch, y2, ch, B2P);
                 PK_FMA(ch, y2, ch, B1P);
                 PK_FMA(ch, y2, ch, B0P);
        // s = sin(2 pi r) = 2 sh ch ; c = cos(2 pi r) = 1 - 2 sh^2
        v2f sh2; PK_ADD(sh2, sh, sh);
        v2f s;   PK_MUL(s, sh2, ch);
        v2f t2;  PK_MUL(t2, sh2, sh);
        v2f c;   PK_SUB(c, ONEP, t2);

        v2f nsp; PK_MUL(nsp, n2, s);     // (n0*s0, n1*s1)
        v2f isp; PK_MUL(isp, rn2, s);    // (is0, is1)

        // layer 2g (lane LO of the pair)
        v2f t0, pn, t1, qn;
        PK_MUL_BCLO(t0, p, c);
        PK_FMA_BCLO_NEGHI(pn, q, nsp, t0);
        PK_MUL_BCLO(t1, q, c);
        PK_FMA_BCLO_NEGLO(qn, p, isp, t1);   // uses OLD p
        p = pn; q = qn;
        // layer 2g+1 (lane HI of the pair)
        PK_MUL_BCHI(t0, p, c);
        PK_FMA_BCHI_NEGHI(pn, q, nsp, t0);
        PK_MUL_BCHI(t1, q, c);
        PK_FMA_BCHI_NEGLO(qn, p, isp, t1);
        p = pn; q = qn;
    }

    const float a  = p.x;
    const float cc = p.y;
    const float bb = q.x;
    const float dd = q.y;

    const float n_in  = s_edge[0];
    const float n_sub = s_edge[1];

    // E = a + eps_Y + i*(bb*n_sub);  H = dd*n_sub + i*cc
    const float Er = a + EPS_Y;
    const float Ei = bb * n_sub;
    const float Hr = dd * n_sub;
    const float Hi = cc;

    const float Nr = fmaf(n_in, Er, -Hr);
    const float Ni = fmaf(n_in, Ei, -Hi);
    const float Dr = fmaf(n_in, Er,  Hr);
    const float Di = fmaf(n_in, Ei,  Hi);

    const float R = (Nr * Nr + Ni * Ni) / (Dr * Dr + Di * Di);
    out[b * W + w] = R;
}

extern "C" void kernel_launch(void* const* d_in, const int* in_sizes, int n_in,
                              void* d_out, int out_size, void* d_ws, size_t ws_size,
                              hipStream_t stream)
{
    const float* n_layers    = (const float*)d_in[0];
    const float* d_layers    = (const float*)d_in[1];
    const float* wavelengths = (const float*)d_in[2];
    float* out = (float*)d_out;

    dim3 grid(W / 256, B);
    dim3 block(256);
    tmm_kernel<<<grid, block, 0, stream>>>(n_layers, d_layers, wavelengths, out);
}

// Round 5
// 104.335 us; speedup vs baseline: 1.1606x; 1.1606x over previous
//
#include <hip/hip_runtime.h>
#include <math.h>

// Problem constants (fixed by the reference file)
constexpr int B  = 1024;
constexpr int NL = 64;
constexpr int W  = 2048;
constexpr int INNER = NL - 2;   // layers 1..62
constexpr float EPS_N = 1e-8f;
constexpr float EPS_Y = 1e-9f;

// One thread handles TWO wavelengths (w, w+1024) of one batch b: the per-layer
// ds_read_b128 and loop overhead amortize over two chains, and the two
// independent chains provide ILP to hide sin/cos latency.
//
// phi tracked in REVOLUTIONS (v_sin_f32/v_cos_f32 take revolutions), so
// phi_rev = n*d/lambda, zero range-reduction ops (|phi_rev| <= ~1.4).
//
// Per layer per wavelength the instruction stream is exactly:
//   1 v_mul (phi) + v_sin + v_cos + 2 v_mul (ns, is) + 4 v_mul + 4 v_fma
// with all negations folded into VOP3 input modifiers (written as fmaf(x,-y,z)).
__global__ __launch_bounds__(256)
void tmm_kernel(const float* __restrict__ n_layers,
                const float* __restrict__ d_layers,
                const float* __restrict__ wavelengths,
                float* __restrict__ out)
{
    __shared__ float4 s_layer[INNER];   // (n*d, n, 1/(n+eps), pad)
    __shared__ float s_edge[2];         // n_in, n_sub

    const int b   = blockIdx.y;
    const int tid = threadIdx.x;
    const int w0  = blockIdx.x * 256 + tid;        // first wavelength
    const int w1  = w0 + (W / 2);                  // second wavelength

    if (tid < INNER) {
        const float n = n_layers[b * NL + 1 + tid];
        const float d = d_layers[b * NL + 1 + tid];
        s_layer[tid] = make_float4(n * d, n, 1.0f / (n + EPS_N), 0.0f);
    }
    if (tid == INNER) {
        s_edge[0] = n_layers[b * NL];              // n_in
        s_edge[1] = n_layers[b * NL + NL - 1];     // n_sub
    }
    __syncthreads();

    const float il0 = 1.0f / wavelengths[w0];      // k0 in revolutions
    const float il1 = 1.0f / wavelengths[w1];

    // Chain 0 state: M = [[a, i*bb],[i*cc, dd]], identity start.
    float a0 = 1.0f, b0 = 0.0f, c0 = 0.0f, d0 = 1.0f;
    // Chain 1 state.
    float a1 = 1.0f, b1 = 0.0f, c1 = 0.0f, d1 = 1.0f;

    #pragma unroll
    for (int i = 0; i < INNER; ++i) {
        const float4 L = s_layer[i];

        const float phi0 = L.x * il0;
        const float phi1 = L.x * il1;
        const float s0 = __builtin_amdgcn_sinf(phi0);
        const float cs0 = __builtin_amdgcn_cosf(phi0);
        const float s1 = __builtin_amdgcn_sinf(phi1);
        const float cs1 = __builtin_amdgcn_cosf(phi1);

        {
            const float ns = L.y * s0;
            const float is = L.z * s0;
            const float na = fmaf(b0,  ns, a0 * cs0);
            const float nb = fmaf(a0, -is, b0 * cs0);
            const float nc = fmaf(d0, -ns, c0 * cs0);
            const float nd = fmaf(c0,  is, d0 * cs0);
            a0 = na; b0 = nb; c0 = nc; d0 = nd;
        }
        {
            const float ns = L.y * s1;
            const float is = L.z * s1;
            const float na = fmaf(b1,  ns, a1 * cs1);
            const float nb = fmaf(a1, -is, b1 * cs1);
            const float nc = fmaf(d1, -ns, c1 * cs1);
            const float nd = fmaf(c1,  is, d1 * cs1);
            a1 = na; b1 = nb; c1 = nc; d1 = nd;
        }
    }

    const float n_in  = s_edge[0];
    const float n_sub = s_edge[1];

    // E = a + eps_Y + i*(b*n_sub);  H = d*n_sub + i*c;  R = |nE-H|^2/|nE+H|^2
    {
        const float Er = a0 + EPS_Y;
        const float Ei = b0 * n_sub;
        const float Hr = d0 * n_sub;
        const float Hi = c0;
        const float Nr = fmaf(n_in, Er, -Hr);
        const float Ni = fmaf(n_in, Ei, -Hi);
        const float Dr = fmaf(n_in, Er,  Hr);
        const float Di = fmaf(n_in, Ei,  Hi);
        out[b * W + w0] = (Nr * Nr + Ni * Ni) / (Dr * Dr + Di * Di);
    }
    {
        const float Er = a1 + EPS_Y;
        const float Ei = b1 * n_sub;
        const float Hr = d1 * n_sub;
        const float Hi = c1;
        const float Nr = fmaf(n_in, Er, -Hr);
        const float Ni = fmaf(n_in, Ei, -Hi);
        const float Dr = fmaf(n_in, Er,  Hr);
        const float Di = fmaf(n_in, Ei,  Hi);
        out[b * W + w1] = (Nr * Nr + Ni * Ni) / (Dr * Dr + Di * Di);
    }
}

extern "C" void kernel_launch(void* const* d_in, const int* in_sizes, int n_in,
                              void* d_out, int out_size, void* d_ws, size_t ws_size,
                              hipStream_t stream)
{
    const float* n_layers    = (const float*)d_in[0];
    const float* d_layers    = (const float*)d_in[1];
    const float* wavelengths = (const float*)d_in[2];
    float* out = (float*)d_out;

    dim3 grid((W / 2) / 256, B);   // 4 x 1024 blocks, 2 wavelengths/thread
    dim3 block(256);
    tmm_kernel<<<grid, block, 0, stream>>>(n_layers, d_layers, wavelengths, out);
}